// Round 4
// baseline (1560.395 us; speedup 1.0000x reference)
//
#include <hip/hip_runtime.h>
#include <hip/hip_bf16.h>

#define BATCH 131072
#define H 256
#define NBLK 8
#define NMID 3
#define MS 32            // samples per workgroup
#define RT_N 6           // (3 streams * MS) / 16 row-tiles
#define NT 512           // 8 waves; each wave owns 2 column-tiles (32 cols)
#define CT_N 2

typedef __attribute__((ext_vector_type(8))) short short8;   // 8 bf16 = 4 VGPRs (MFMA A/B frag)
typedef __attribute__((ext_vector_type(4))) float f32x4;    // MFMA C/D frag

// pack two f32 -> packed bf16 pair (round-half-up): 2 adds + v_perm.
__device__ __forceinline__ unsigned pk2(float a, float b) {
    unsigned ua = __float_as_uint(a) + 0x8000u;
    unsigned ub = __float_as_uint(b) + 0x8000u;
    return __builtin_amdgcn_perm(ub, ua, 0x07060302u);
}

// Pack Wm into MFMA B-frag order bf16, column-permuted for 8-wave/2-ct epilogue:
// tile T = wave*2+ct covers cols n = (T>>1)*32 + m*2 + (T&1), m = lane&15
// => epilogue thread owns 2 consecutive columns (b32 stores, 2 lanes/bank = free).
__global__ void pack_w_kernel(const float* __restrict__ Wm, unsigned short* __restrict__ Wp) {
    int o = blockIdx.x * blockDim.x + threadIdx.x;   // 24 * 8192 chunks
    if (o >= NBLK * NMID * 8192) return;
    int lane  = o & 63;
    int T     = (o >> 6) & 15;
    int kk    = (o >> 10) & 7;
    int layer = o >> 13;
    int n  = (T >> 1) * 32 + (lane & 15) * 2 + (T & 1);
    int k0 = kk * 32 + (lane >> 4) * 8;
    const float* src = Wm + (size_t)layer * H * H;
    unsigned int w[4];
    #pragma unroll
    for (int jj = 0; jj < 4; ++jj)
        w[jj] = pk2(src[(size_t)(k0 + 2*jj) * H + n], src[(size_t)(k0 + 2*jj + 1) * H + n]);
    uint4 val; val.x = w[0]; val.y = w[1]; val.z = w[2]; val.w = w[3];
    ((uint4*)Wp)[o] = val;
}

struct Packs { unsigned ph[2][4]; unsigned pa[2][4]; unsigned pb[2][4]; };

// bias+ReLU on primal, mask tangents, pack to bf16 — registers only, no LDS.
__device__ __forceinline__ void epi_compute(const f32x4 (&acc)[RT_N][CT_N],
                                            const float2 bv, Packs& p) {
    #pragma unroll
    for (int g = 0; g < 2; ++g) {
        #pragma unroll
        for (int r = 0; r < 4; ++r) {
            float c0 = acc[g][0][r] + bv.x;
            float c1 = acc[g][1][r] + bv.y;
            bool m0 = c0 > 0.0f, m1 = c1 > 0.0f;
            p.ph[g][r] = pk2(m0 ? c0 : 0.0f,             m1 ? c1 : 0.0f);
            p.pa[g][r] = pk2(m0 ? acc[2+g][0][r] : 0.0f, m1 ? acc[2+g][1][r] : 0.0f);
            p.pb[g][r] = pk2(m0 ? acc[4+g][0][r] : 0.0f, m1 ? acc[4+g][1][r] : 0.0f);
        }
    }
}

// write next layer's A-frag X; thread cols nb = wave*32 + mcol*2 => kkx = wave.
__device__ __forceinline__ void epi_store(const Packs& p, unsigned short* __restrict__ Xs,
                                          int wave, int lane) {
    const int mcol = lane & 15, quad = lane >> 4;
    const int qx = (mcol >> 2) & 3;
    const int jb = (mcol & 3) * 2;
    #pragma unroll
    for (int g = 0; g < 2; ++g) {
        #pragma unroll
        for (int r = 0; r < 4; ++r) {
            int le  = qx * 16 + quad * 4 + r;
            int scl = le ^ ((le >> 3) & 7);
            int e0  = ((g * 8 + wave) * 64 + scl) * 8 + jb;
            *(unsigned*)(Xs + e0)         = p.ph[g][r];
            *(unsigned*)(Xs + e0 + 8192)  = p.pa[g][r];   // ta rows: rt offset +2
            *(unsigned*)(Xs + e0 + 16384) = p.pb[g][r];   // tb rows: rt offset +4
        }
    }
}

__global__ __launch_bounds__(NT, 4)
void flow_kernel(const float* __restrict__ x, const float* __restrict__ v,
                 const float* __restrict__ Wi, const float* __restrict__ bi,
                 const float* __restrict__ bm, const float* __restrict__ Wo,
                 const float* __restrict__ bo,
                 const unsigned short* __restrict__ Wp,
                 float* __restrict__ out)
{
    __shared__ uint4 Xl4[RT_N * 8 * 64];     // 48 KiB
    __shared__ float zbuf[MS * 2];
    __shared__ float vbuf[MS * 2];

    unsigned short* Xs = (unsigned short*)Xl4;

    const int tid  = threadIdx.x;
    const int wave = tid >> 6;
    const int lane = tid & 63;
    const int mcol = lane & 15;
    const int quad = lane >> 4;
    const int s0   = blockIdx.x * MS;
    const int rl   = lane ^ ((lane >> 3) & 7);   // swizzled A-read slot

    float dlp = 0.0f;
    if (tid < MS) {
        zbuf[tid*2+0] = x[(size_t)(s0+tid)*2+0];
        zbuf[tid*2+1] = x[(size_t)(s0+tid)*2+1];
        vbuf[tid*2+0] = v[(size_t)(s0+tid)*2+0];
        vbuf[tid*2+1] = v[(size_t)(s0+tid)*2+1];
    }
    __syncthreads();

    for (int b = 0; b < NBLK; ++b) {
        // ------- layer 0: 2 -> 256 via MFMA; A and B frags built in registers -------
        {
            const float* Wi0 = Wi + (size_t)b * 2 * H;
            const float* Wi1 = Wi0 + H;
            short8 b0[CT_N];
            #pragma unroll
            for (int ct = 0; ct < CT_N; ++ct) {
                short8 z = {0,0,0,0,0,0,0,0};
                if (quad == 0) {                       // only k=0,1 rows nonzero
                    int n = wave * 32 + mcol * 2 + ct;
                    unsigned p = pk2(Wi0[n], Wi1[n]);
                    z[0] = (short)(p & 0xFFFFu);
                    z[1] = (short)(p >> 16);
                }
                b0[ct] = z;
            }
            f32x4 acc[RT_N][CT_N];
            #pragma unroll
            for (int rt = 0; rt < RT_N; ++rt)
                #pragma unroll
                for (int ct = 0; ct < CT_N; ++ct)
                    acc[rt][ct] = (f32x4){0.f, 0.f, 0.f, 0.f};
            #pragma unroll
            for (int rt = 0; rt < RT_N; ++rt) {
                short8 af = {0,0,0,0,0,0,0,0};
                int st = rt >> 1;
                if (quad == 0) {
                    if (st == 0) {
                        int s = (rt & 1) * 16 + mcol;
                        unsigned p = pk2(zbuf[s*2+0], zbuf[s*2+1]);
                        af[0] = (short)(p & 0xFFFFu);
                        af[1] = (short)(p >> 16);
                    } else if (st == 1) af[0] = (short)0x3F80;   // e0=(1,0)
                    else                af[1] = (short)0x3F80;   // e1=(0,1)
                }
                #pragma unroll
                for (int ct = 0; ct < CT_N; ++ct)
                    acc[rt][ct] = __builtin_amdgcn_mfma_f32_16x16x32_bf16(af, b0[ct], acc[rt][ct], 0, 0, 0);
            }
            Packs p;
            epi_compute(acc, *(const float2*)(bi + (size_t)b * H + wave*32 + mcol*2), p);
            epi_store(p, Xs, wave, lane);   // no X readers in flight at block start
            __syncthreads();
        }

        // ------- mid layers: 3x (256 -> 256) via MFMA -------
        for (int li = 0; li < NMID; ++li) {
            const int layer = b * NMID + li;
            const short8* Bp = ((const short8*)Wp) + (size_t)layer * 8192;

            f32x4 acc[RT_N][CT_N];
            #pragma unroll
            for (int rt = 0; rt < RT_N; ++rt)
                #pragma unroll
                for (int ct = 0; ct < CT_N; ++ct)
                    acc[rt][ct] = (f32x4){0.f, 0.f, 0.f, 0.f};

            #pragma unroll
            for (int kk = 0; kk < 8; ++kk) {
                short8 bf[CT_N];
                #pragma unroll
                for (int ct = 0; ct < CT_N; ++ct)
                    bf[ct] = Bp[(kk*16 + wave*2 + ct)*64 + lane];        // coalesced b128 (L2-hot)
                #pragma unroll
                for (int rt = 0; rt < RT_N; ++rt) {
                    short8 af = ((const short8*)Xl4)[(rt*8 + kk)*64 + rl]; // ds_read_b128
                    #pragma unroll
                    for (int ct = 0; ct < CT_N; ++ct)
                        acc[rt][ct] = __builtin_amdgcn_mfma_f32_16x16x32_bf16(af, bf[ct], acc[rt][ct], 0, 0, 0);
                }
            }
            Packs p;
            epi_compute(acc, *(const float2*)(bm + (size_t)layer * H + wave*32 + mcol*2), p);
            __syncthreads();                 // all waves done READING X
            epi_store(p, Xs, wave, lane);    // only stores between the two barriers
            __syncthreads();
        }

        // ------- layer 4: 256 -> 2 via MFMA (N padded 16, K split across 8 waves) -------
        {
            const float* Wob = Wo + (size_t)b * H * 2;
            const float* bob = bo + (size_t)b * 2;
            short8 b4 = {0,0,0,0,0,0,0,0};
            if (mcol < 2) {
                int kb = wave * 32 + quad * 8;
                #pragma unroll
                for (int jj = 0; jj < 4; ++jj) {
                    unsigned p = pk2(Wob[(kb + 2*jj) * 2 + mcol], Wob[(kb + 2*jj + 1) * 2 + mcol]);
                    b4[2*jj]   = (short)(p & 0xFFFFu);
                    b4[2*jj+1] = (short)(p >> 16);
                }
            }
            f32x4 accL[RT_N];
            #pragma unroll
            for (int rt = 0; rt < RT_N; ++rt) accL[rt] = (f32x4){0.f, 0.f, 0.f, 0.f};
            #pragma unroll
            for (int rt = 0; rt < RT_N; ++rt) {
                short8 af = ((const short8*)Xl4)[(rt*8 + wave)*64 + rl];  // wave's K-slice
                accL[rt] = __builtin_amdgcn_mfma_f32_16x16x32_bf16(af, b4, accL[rt], 0, 0, 0);
            }
            __syncthreads();                 // X dead; overlay partials
            float* part = (float*)Xl4;       // [96 rows][2 cols][8 waves] = 1536 floats
            if (mcol < 2) {
                #pragma unroll
                for (int rt = 0; rt < RT_N; ++rt)
                    #pragma unroll
                    for (int r = 0; r < 4; ++r)
                        part[((rt*16 + quad*4 + r)*2 + mcol)*8 + wave] = accL[rt][r];
            }
            __syncthreads();
            float* res = part + 1536;        // 192 floats
            if (tid < 192) {
                float4 p0 = ((const float4*)part)[tid*2];
                float4 p1 = ((const float4*)part)[tid*2+1];
                res[tid] = (p0.x + p0.y + p0.z + p0.w) + (p1.x + p1.y + p1.z + p1.w);
            }
            __syncthreads();
            if (tid < MS) {
                float SH0 = res[tid*2],       SH1 = res[tid*2+1];
                float SA0 = res[64 + tid*2],  SA1 = res[65 + tid*2];
                float SB0 = res[128 + tid*2], SB1 = res[129 + tid*2];
                float pre0 = SH0 + bob[0], pre1 = SH1 + bob[1];
                bool  m0 = pre0 > 0.f,     m1 = pre1 > 0.f;
                float gx0 = m0 ? pre0 : 0.f, gx1 = m1 ? pre1 : 0.f;
                float J00 = m0 ? SA0 : 0.f;
                float J01 = m0 ? SB0 : 0.f;
                float J10 = m1 ? SA1 : 0.f;
                float J11 = m1 ? SB1 : 0.f;
                float v0 = vbuf[tid*2+0], v1 = vbuf[tid*2+1];
                float w0 = v0, w1 = v1, ld = 0.f;
                const float coef[5] = {1.f, -0.5f, 1.f/3.f, -0.25f, 0.2f};
                #pragma unroll
                for (int k = 0; k < 5; ++k) {
                    float nw0 = fmaf(J00, w0, J01 * w1);
                    float nw1 = fmaf(J10, w0, J11 * w1);
                    w0 = nw0; w1 = nw1;
                    ld = fmaf(coef[k], fmaf(w0, v0, w1 * v1), ld);
                }
                zbuf[tid*2+0] += gx0;
                zbuf[tid*2+1] += gx1;
                dlp -= ld;
            }
            __syncthreads();
        }
    }

    if (tid < MS) {
        out[(size_t)(s0+tid)*2+0] = zbuf[tid*2+0];
        out[(size_t)(s0+tid)*2+1] = zbuf[tid*2+1];
        out[(size_t)2*BATCH + s0 + tid] = dlp;
    }
}

extern "C" void kernel_launch(void* const* d_in, const int* in_sizes, int n_in,
                              void* d_out, int out_size, void* d_ws, size_t ws_size,
                              hipStream_t stream) {
    const float* x  = (const float*)d_in[0];
    const float* v  = (const float*)d_in[1];
    const float* Wi = (const float*)d_in[2];
    const float* bi = (const float*)d_in[3];
    const float* Wm = (const float*)d_in[4];
    const float* bm = (const float*)d_in[5];
    const float* Wo = (const float*)d_in[6];
    const float* bo = (const float*)d_in[7];
    unsigned short* Wp = (unsigned short*)d_ws;   // 24*65536*2 = 3 MiB

    int nchunks = NBLK * NMID * 8192;
    pack_w_kernel<<<(nchunks + 255) / 256, 256, 0, stream>>>(Wm, Wp);
    flow_kernel<<<BATCH / MS, NT, 0, stream>>>(x, v, Wi, bi, bm, Wo, bo, Wp, (float*)d_out);
}

// Round 5
// 1261.966 us; speedup vs baseline: 1.2365x; 1.2365x over previous
//
#include <hip/hip_runtime.h>
#include <hip/hip_bf16.h>

#define BATCH 131072
#define H 256
#define NBLK 8
#define NMID 3
#define MS 16            // samples per workgroup
#define RT_N 3           // 3 streams x 1 row-tile (16 samples)
#define NT 256           // 4 waves; each wave owns 4 column-tiles
#define CT_N 4

typedef __attribute__((ext_vector_type(8))) short short8;   // 8 bf16 = 4 VGPRs (MFMA A/B frag)
typedef __attribute__((ext_vector_type(4))) float f32x4;    // MFMA C/D frag

// pack two f32 -> packed bf16 pair (round-half-up): 2 adds + v_perm.
__device__ __forceinline__ unsigned pk2(float a, float b) {
    unsigned ua = __float_as_uint(a) + 0x8000u;
    unsigned ub = __float_as_uint(b) + 0x8000u;
    return __builtin_amdgcn_perm(ub, ua, 0x07060302u);
}

// Pack Wm into MFMA B-frag order bf16, column-permuted so each epilogue thread
// owns cols {c,c+1} and {c+32,c+33}, c = wave*64 + mcol*2:
//   tile T = wave*4+ct covers n = (T>>2)*64 + (T&1)*32 + m*2 + ((T>>1)&1).
// => epilogue is pure b32 stores, 2 lanes/bank (free).
__global__ void pack_w_kernel(const float* __restrict__ Wm, unsigned short* __restrict__ Wp) {
    int o = blockIdx.x * blockDim.x + threadIdx.x;   // 24 * 8192 chunks
    if (o >= NBLK * NMID * 8192) return;
    int lane  = o & 63;
    int T     = (o >> 6) & 15;
    int kk    = (o >> 10) & 7;
    int layer = o >> 13;
    int n  = (T >> 2) * 64 + (T & 1) * 32 + (lane & 15) * 2 + ((T >> 1) & 1);
    int k0 = kk * 32 + (lane >> 4) * 8;
    const float* src = Wm + (size_t)layer * H * H;
    unsigned int w[4];
    #pragma unroll
    for (int jj = 0; jj < 4; ++jj)
        w[jj] = pk2(src[(size_t)(k0 + 2*jj) * H + n], src[(size_t)(k0 + 2*jj + 1) * H + n]);
    uint4 val; val.x = w[0]; val.y = w[1]; val.z = w[2]; val.w = w[3];
    ((uint4*)Wp)[o] = val;
}

struct Packs { unsigned ph[4][2]; unsigned pa[4][2]; unsigned pb[4][2]; };  // [r][colgrp]

// bias+ReLU on primal, mask tangents, pack to bf16 — registers only.
// col group 0 = ct pair (0,2) -> cols c,c+1 ; group 1 = ct pair (1,3) -> c+32,c+33.
__device__ __forceinline__ void epi_compute(const f32x4 (&acc)[RT_N][CT_N],
                                            const float2 bvA, const float2 bvB, Packs& p) {
    #pragma unroll
    for (int r = 0; r < 4; ++r) {
        float a0 = acc[0][0][r] + bvA.x, a1 = acc[0][2][r] + bvA.y;
        float b0 = acc[0][1][r] + bvB.x, b1 = acc[0][3][r] + bvB.y;
        bool ma0 = a0 > 0.f, ma1 = a1 > 0.f, mb0 = b0 > 0.f, mb1 = b1 > 0.f;
        p.ph[r][0] = pk2(ma0 ? a0 : 0.f,            ma1 ? a1 : 0.f);
        p.ph[r][1] = pk2(mb0 ? b0 : 0.f,            mb1 ? b1 : 0.f);
        p.pa[r][0] = pk2(ma0 ? acc[1][0][r] : 0.f,  ma1 ? acc[1][2][r] : 0.f);
        p.pa[r][1] = pk2(mb0 ? acc[1][1][r] : 0.f,  mb1 ? acc[1][3][r] : 0.f);
        p.pb[r][0] = pk2(ma0 ? acc[2][0][r] : 0.f,  ma1 ? acc[2][2][r] : 0.f);
        p.pb[r][1] = pk2(mb0 ? acc[2][1][r] : 0.f,  mb1 ? acc[2][3][r] : 0.f);
    }
}

// write next layer's A-frag X. X layout: [3 st][8 kk][64 slots][8 bf16].
__device__ __forceinline__ void epi_store(const Packs& p, unsigned short* __restrict__ Xs,
                                          int wave, int lane) {
    const int mcol = lane & 15, quad = lane >> 4;
    const int qx = mcol >> 2;
    const int jb = (mcol & 3) * 2;
    const int kkA = wave * 2;                     // cols c..c+1 live in kk=wave*2
    #pragma unroll
    for (int r = 0; r < 4; ++r) {
        int le  = qx * 16 + quad * 4 + r;
        int scl = le ^ ((le >> 3) & 7);
        int e0  = kkA * 512 + scl * 8 + jb;       // st=0 base; +512 => kk+1; +4096 per st
        *(unsigned*)(Xs + e0)               = p.ph[r][0];
        *(unsigned*)(Xs + e0 + 512)         = p.ph[r][1];
        *(unsigned*)(Xs + e0 + 4096)        = p.pa[r][0];
        *(unsigned*)(Xs + e0 + 4096 + 512)  = p.pa[r][1];
        *(unsigned*)(Xs + e0 + 8192)        = p.pb[r][0];
        *(unsigned*)(Xs + e0 + 8192 + 512)  = p.pb[r][1];
    }
}

__global__ __launch_bounds__(NT, 3)
void flow_kernel(const float* __restrict__ x, const float* __restrict__ v,
                 const float* __restrict__ Wi, const float* __restrict__ bi,
                 const float* __restrict__ bm, const float* __restrict__ Wo,
                 const float* __restrict__ bo,
                 const unsigned short* __restrict__ Wp,
                 float* __restrict__ out)
{
    __shared__ uint4 Xl4[RT_N * 8 * 64];     // 1536 chunks * 16B = 24 KiB
    __shared__ float zbuf[MS * 2];
    __shared__ float vbuf[MS * 2];

    unsigned short* Xs = (unsigned short*)Xl4;

    const int tid  = threadIdx.x;
    const int wave = tid >> 6;
    const int lane = tid & 63;
    const int mcol = lane & 15;
    const int quad = lane >> 4;
    const int s0   = blockIdx.x * MS;
    const int rl   = lane ^ ((lane >> 3) & 7);   // swizzled A-read slot

    float dlp = 0.0f;
    if (tid < MS) {
        zbuf[tid*2+0] = x[(size_t)(s0+tid)*2+0];
        zbuf[tid*2+1] = x[(size_t)(s0+tid)*2+1];
        vbuf[tid*2+0] = v[(size_t)(s0+tid)*2+0];
        vbuf[tid*2+1] = v[(size_t)(s0+tid)*2+1];
    }
    __syncthreads();

    const int cA = wave * 64 + mcol * 2;         // this thread's first col (group A); +32 = group B

    for (int b = 0; b < NBLK; ++b) {
        // ------- layer 0: 2 -> 256 via MFMA; A and B frags built in registers -------
        {
            const float* Wi0 = Wi + (size_t)b * 2 * H;
            const float* Wi1 = Wi0 + H;
            short8 b0[CT_N];
            #pragma unroll
            for (int ct = 0; ct < CT_N; ++ct) {
                short8 z = {0,0,0,0,0,0,0,0};
                if (quad == 0) {                       // only k=0,1 rows nonzero
                    int n = cA + (ct & 1) * 32 + (ct >> 1);
                    unsigned p = pk2(Wi0[n], Wi1[n]);
                    z[0] = (short)(p & 0xFFFFu);
                    z[1] = (short)(p >> 16);
                }
                b0[ct] = z;
            }
            f32x4 acc[RT_N][CT_N];
            #pragma unroll
            for (int st = 0; st < RT_N; ++st)
                #pragma unroll
                for (int ct = 0; ct < CT_N; ++ct)
                    acc[st][ct] = (f32x4){0.f, 0.f, 0.f, 0.f};
            #pragma unroll
            for (int st = 0; st < RT_N; ++st) {
                short8 af = {0,0,0,0,0,0,0,0};
                if (quad == 0) {
                    if (st == 0) {
                        unsigned p = pk2(zbuf[mcol*2+0], zbuf[mcol*2+1]);
                        af[0] = (short)(p & 0xFFFFu);
                        af[1] = (short)(p >> 16);
                    } else if (st == 1) af[0] = (short)0x3F80;   // e0=(1,0)
                    else                af[1] = (short)0x3F80;   // e1=(0,1)
                }
                #pragma unroll
                for (int ct = 0; ct < CT_N; ++ct)
                    acc[st][ct] = __builtin_amdgcn_mfma_f32_16x16x32_bf16(af, b0[ct], acc[st][ct], 0, 0, 0);
            }
            Packs p;
            const float* bib = bi + (size_t)b * H;
            epi_compute(acc, *(const float2*)(bib + cA), *(const float2*)(bib + cA + 32), p);
            epi_store(p, Xs, wave, lane);   // X has no readers at block start
            __syncthreads();
        }

        // ------- mid layers: 3x (256 -> 256) via MFMA -------
        for (int li = 0; li < NMID; ++li) {
            const int layer = b * NMID + li;
            const short8* Bp = ((const short8*)Wp) + (size_t)layer * 8192;

            f32x4 acc[RT_N][CT_N];
            #pragma unroll
            for (int st = 0; st < RT_N; ++st)
                #pragma unroll
                for (int ct = 0; ct < CT_N; ++ct)
                    acc[st][ct] = (f32x4){0.f, 0.f, 0.f, 0.f};

            #pragma unroll
            for (int kk = 0; kk < 8; ++kk) {
                short8 bf[CT_N];
                #pragma unroll
                for (int ct = 0; ct < CT_N; ++ct)
                    bf[ct] = Bp[(kk*16 + wave*4 + ct)*64 + lane];        // coalesced b128 (L2-hot)
                #pragma unroll
                for (int st = 0; st < RT_N; ++st) {
                    short8 af = ((const short8*)Xl4)[(st*8 + kk)*64 + rl]; // ds_read_b128
                    #pragma unroll
                    for (int ct = 0; ct < CT_N; ++ct)
                        acc[st][ct] = __builtin_amdgcn_mfma_f32_16x16x32_bf16(af, bf[ct], acc[st][ct], 0, 0, 0);
                }
            }
            Packs p;
            const float* bmb = bm + (size_t)layer * H;
            epi_compute(acc, *(const float2*)(bmb + cA), *(const float2*)(bmb + cA + 32), p);
            __syncthreads();                 // all waves done READING X
            epi_store(p, Xs, wave, lane);    // only stores between the two barriers
            __syncthreads();
        }

        // ------- layer 4: 256 -> 2 via MFMA (N padded 16; wave owns kk = wave*2..+1) -------
        {
            const float* Wob = Wo + (size_t)b * H * 2;
            const float* bob = bo + (size_t)b * 2;
            short8 b4[2];
            #pragma unroll
            for (int kki = 0; kki < 2; ++kki) {
                short8 z = {0,0,0,0,0,0,0,0};
                if (mcol < 2) {
                    int kb = (wave * 2 + kki) * 32 + quad * 8;
                    #pragma unroll
                    for (int jj = 0; jj < 4; ++jj) {
                        unsigned p = pk2(Wob[(kb + 2*jj) * 2 + mcol], Wob[(kb + 2*jj + 1) * 2 + mcol]);
                        z[2*jj]   = (short)(p & 0xFFFFu);
                        z[2*jj+1] = (short)(p >> 16);
                    }
                }
                b4[kki] = z;
            }
            f32x4 accL[RT_N];
            #pragma unroll
            for (int st = 0; st < RT_N; ++st) accL[st] = (f32x4){0.f, 0.f, 0.f, 0.f};
            #pragma unroll
            for (int st = 0; st < RT_N; ++st) {
                #pragma unroll
                for (int kki = 0; kki < 2; ++kki) {
                    short8 af = ((const short8*)Xl4)[(st*8 + wave*2 + kki)*64 + rl];
                    accL[st] = __builtin_amdgcn_mfma_f32_16x16x32_bf16(af, b4[kki], accL[st], 0, 0, 0);
                }
            }
            __syncthreads();                 // X dead; overlay partials
            float* part = (float*)Xl4;       // [48 rows][2 cols][4 waves] = 384 floats
            if (mcol < 2) {
                #pragma unroll
                for (int st = 0; st < RT_N; ++st)
                    #pragma unroll
                    for (int r = 0; r < 4; ++r)
                        part[((st*16 + quad*4 + r)*2 + mcol)*4 + wave] = accL[st][r];
            }
            __syncthreads();
            float* res = part + 384;         // 96 floats: ((st*16+row)*2+m)
            if (tid < 96) {
                float4 p4 = ((const float4*)part)[tid];
                res[tid] = p4.x + p4.y + p4.z + p4.w;
            }
            __syncthreads();
            if (tid < MS) {
                float SH0 = res[tid*2],      SH1 = res[tid*2+1];
                float SA0 = res[32 + tid*2], SA1 = res[33 + tid*2];
                float SB0 = res[64 + tid*2], SB1 = res[65 + tid*2];
                float pre0 = SH0 + bob[0], pre1 = SH1 + bob[1];
                bool  m0 = pre0 > 0.f,     m1 = pre1 > 0.f;
                float gx0 = m0 ? pre0 : 0.f, gx1 = m1 ? pre1 : 0.f;
                float J00 = m0 ? SA0 : 0.f;
                float J01 = m0 ? SB0 : 0.f;
                float J10 = m1 ? SA1 : 0.f;
                float J11 = m1 ? SB1 : 0.f;
                float v0 = vbuf[tid*2+0], v1 = vbuf[tid*2+1];
                float w0 = v0, w1 = v1, ld = 0.f;
                const float coef[5] = {1.f, -0.5f, 1.f/3.f, -0.25f, 0.2f};
                #pragma unroll
                for (int k = 0; k < 5; ++k) {
                    float nw0 = fmaf(J00, w0, J01 * w1);
                    float nw1 = fmaf(J10, w0, J11 * w1);
                    w0 = nw0; w1 = nw1;
                    ld = fmaf(coef[k], fmaf(w0, v0, w1 * v1), ld);
                }
                zbuf[tid*2+0] += gx0;
                zbuf[tid*2+1] += gx1;
                dlp -= ld;
            }
            __syncthreads();
        }
    }

    if (tid < MS) {
        out[(size_t)(s0+tid)*2+0] = zbuf[tid*2+0];
        out[(size_t)(s0+tid)*2+1] = zbuf[tid*2+1];
        out[(size_t)2*BATCH + s0 + tid] = dlp;
    }
}

extern "C" void kernel_launch(void* const* d_in, const int* in_sizes, int n_in,
                              void* d_out, int out_size, void* d_ws, size_t ws_size,
                              hipStream_t stream) {
    const float* x  = (const float*)d_in[0];
    const float* v  = (const float*)d_in[1];
    const float* Wi = (const float*)d_in[2];
    const float* bi = (const float*)d_in[3];
    const float* Wm = (const float*)d_in[4];
    const float* bm = (const float*)d_in[5];
    const float* Wo = (const float*)d_in[6];
    const float* bo = (const float*)d_in[7];
    unsigned short* Wp = (unsigned short*)d_ws;   // 24*65536*2 = 3 MiB

    int nchunks = NBLK * NMID * 8192;
    pack_w_kernel<<<(nchunks + 255) / 256, 256, 0, stream>>>(Wm, Wp);
    flow_kernel<<<BATCH / MS, NT, 0, stream>>>(x, v, Wi, bi, bm, Wo, bo, Wp, (float*)d_out);
}